// Round 6
// baseline (468.054 us; speedup 1.0000x reference)
//
#include <hip/hip_runtime.h>
#include <hip/hip_bf16.h>

typedef __hip_bfloat16 bf16;
typedef short bf16x8 __attribute__((ext_vector_type(8)));
typedef float f32x4 __attribute__((ext_vector_type(4)));

__device__ __forceinline__ float gelu_f(float x) {
  return 0.5f * x * (1.f + erff(x * 0.70710678118654752f));
}

__device__ __forceinline__ unsigned short f2bfu(float f) {
  bf16 h = __float2bfloat16(f);
  unsigned short u;
  __builtin_memcpy(&u, &h, 2);
  return u;
}

// async 16B/lane global->LDS; lds dest is wave-uniform base + lane*16
__device__ __forceinline__ void load16_lds(const bf16* g, bf16* l) {
  __builtin_amdgcn_global_load_lds(
      (const __attribute__((address_space(1))) unsigned int*)g,
      (__attribute__((address_space(3))) unsigned int*)l, 16, 0, 0);
}

// ---------------- weight transpose + cast: src fp32 [R][C] -> dst bf16 [C][R]
__global__ __launch_bounds__(256) void transpose_cast(
    const float* __restrict__ src, bf16* __restrict__ dst, int R, int C) {
  __shared__ float tile[32][33];
  int tx = threadIdx.x & 31, ty = threadIdx.x >> 5;  // 32 x 8
  int r0 = blockIdx.y * 32, c0 = blockIdx.x * 32;
  #pragma unroll
  for (int i = ty; i < 32; i += 8)
    tile[i][tx] = src[(size_t)(r0 + i) * C + (c0 + tx)];
  __syncthreads();
  #pragma unroll
  for (int i = ty; i < 32; i += 8)
    dst[(size_t)(c0 + i) * R + (r0 + tx)] = __float2bfloat16(tile[tx][i]);
}

// ---------------- LayerNorm: x fp32 [rows][1024] -> y bf16, one block per row
__global__ __launch_bounds__(256) void ln_kernel(
    const float* __restrict__ x, const float* __restrict__ g,
    const float* __restrict__ b, bf16* __restrict__ y) {
  int row = blockIdx.x;
  int t = threadIdx.x;
  const float4* xr = (const float4*)(x + (size_t)row * 1024);
  float4 v = xr[t];
  float s = v.x + v.y + v.z + v.w;
  float ss = v.x * v.x + v.y * v.y + v.z * v.z + v.w * v.w;
  #pragma unroll
  for (int off = 32; off >= 1; off >>= 1) {
    s += __shfl_xor(s, off);
    ss += __shfl_xor(ss, off);
  }
  __shared__ float red[8];
  int wv = t >> 6;
  if ((t & 63) == 0) { red[wv] = s; red[4 + wv] = ss; }
  __syncthreads();
  float S = red[0] + red[1] + red[2] + red[3];
  float SS = red[4] + red[5] + red[6] + red[7];
  float mu = S * (1.f / 1024.f);
  float var = SS * (1.f / 1024.f) - mu * mu;
  float inv = rsqrtf(var + 1e-5f);
  float4 gv = ((const float4*)g)[t];
  float4 bv = ((const float4*)b)[t];
  ushort4 o;
  o.x = f2bfu((v.x - mu) * inv * gv.x + bv.x);
  o.y = f2bfu((v.y - mu) * inv * gv.y + bv.y);
  o.z = f2bfu((v.z - mu) * inv * gv.z + bv.z);
  o.w = f2bfu((v.w - mu) * inv * gv.w + bv.w);
  ((ushort4*)(y + (size_t)row * 1024))[t] = o;
}

// ---------------- GEMM: C = A[M][K] @ Bt[N][K]^T + bias
// m97 pattern: global_load_lds width-16 staging, non-padded LDS, XOR swizzle,
// double-buffered prefetch.
// EPI 0: fused QKV epilogue; q output prescaled by C=0.125*log2(e) so the
//        attention kernel can use exp2 with no multiply.
// EPI 3: fp32 out = val + resid
// EPI 4: bf16 out = gelu(val)
// EPI 5: fp32 out = gelu(val) + resid
// EPI 6: split-K partial: bf16 partial[z][m][n] = acc (no bias), K-chunk=1024
template <int EPI>
__global__ __launch_bounds__(256) void gemm_bf16(
    const bf16* __restrict__ A, const bf16* __restrict__ Bt,
    const float* __restrict__ bias0, const float* __restrict__ bias1,
    const float* __restrict__ bias2, const float* __restrict__ resid,
    void* __restrict__ C0, void* __restrict__ C1, void* __restrict__ C2,
    int M, int N, int K) {
  __shared__ __align__(16) bf16 As[2][128 * 32];
  __shared__ __align__(16) bf16 Bs[2][128 * 32];
  const int t = threadIdx.x, lane = t & 63, w = t >> 6;
  const int wm = (w >> 1) * 64, wn = (w & 1) * 64;
  const int m0 = blockIdx.y * 128, n0 = blockIdx.x * 128;

  const int koff = (EPI == 6) ? (int)blockIdx.z * 1024 : 0;
  const int kc_len = (EPI == 6) ? 1024 : K;

  const int srow = lane >> 2;   // row within 16-row staging chunk
  const int sgrp = lane & 3;    // LDS col-group position this lane fills
  f32x4 acc[4][4] = {};

  const bf16* Abase = A + (size_t)m0 * K + koff;
  const bf16* Bbase = Bt + (size_t)n0 * K + koff;

  auto stage = [&](int buf, int kt) {
    #pragma unroll
    for (int c = 0; c < 2; ++c) {
      int row = w * 32 + c * 16 + srow;
      int sw = (row & 3) ^ ((row >> 2) & 3);
      int gg = sgrp ^ sw;  // global col-group this lane fetches (swizzled)
      const bf16* ga = Abase + (size_t)row * K + kt + gg * 8;
      const bf16* gb = Bbase + (size_t)row * K + kt + gg * 8;
      load16_lds(ga, &As[buf][(w * 32 + c * 16) * 32]);
      load16_lds(gb, &Bs[buf][(w * 32 + c * 16) * 32]);
    }
  };

  // fragment read col-group (swizzle inverse), uniform over mc/nc:
  // row = (mult of 16) + (lane&15) -> sw = (lane&3)^((lane>>2)&3)
  const int q8 = (((lane >> 4) ^ (lane & 3) ^ ((lane >> 2) & 3))) * 8;
  const int fr = lane & 15;

  const int nk = kc_len >> 5;
  stage(0, 0);
  for (int i = 0; i < nk; ++i) {
    const int cur = i & 1;
    __syncthreads();  // drains vmcnt (staged loads for cur) + barrier
    if (i + 1 < nk) stage(cur ^ 1, (i + 1) << 5);
    bf16x8 af[4], bfr[4];
    #pragma unroll
    for (int mc = 0; mc < 4; ++mc)
      af[mc] = *(const bf16x8*)&As[cur][(wm + mc * 16 + fr) * 32 + q8];
    #pragma unroll
    for (int nc = 0; nc < 4; ++nc)
      bfr[nc] = *(const bf16x8*)&Bs[cur][(wn + nc * 16 + fr) * 32 + q8];
    #pragma unroll
    for (int mc = 0; mc < 4; ++mc)
      #pragma unroll
      for (int nc = 0; nc < 4; ++nc)
        acc[mc][nc] = __builtin_amdgcn_mfma_f32_16x16x32_bf16(
            af[mc], bfr[nc], acc[mc][nc], 0, 0, 0);
  }

  if constexpr (EPI == 0) {
    const int which = n0 >> 10;  // block-uniform: 0=q, 1=k, 2=v
    const float* bp = which == 0 ? bias0 : which == 1 ? bias1 : bias2;
    bf16* qk = (bf16*)(which == 0 ? C0 : C1);
    const float qscale = 0.18033688011112042f;  // 0.125 * log2(e)
    #pragma unroll
    for (int mc = 0; mc < 4; ++mc) {
      #pragma unroll
      for (int reg = 0; reg < 4; ++reg) {
        int m = m0 + wm + mc * 16 + ((lane >> 4) << 2) + reg;
        int b = m >> 11, tok = m & 2047;
        #pragma unroll
        for (int nc = 0; nc < 4; ++nc) {
          int n = n0 + wn + nc * 16 + (lane & 15);
          int nn = n & 1023, hh = nn >> 6, d = n & 63;
          float val = acc[mc][nc][reg] + bp[nn];
          if (which == 2)
            ((bf16*)C2)[(size_t)((b * 16 + hh) * 64 + d) * 2048 + tok] =
                __float2bfloat16(val);
          else if (which == 0)
            qk[(size_t)((b * 16 + hh) * 2048 + tok) * 64 + d] =
                __float2bfloat16(val * qscale);
          else
            qk[(size_t)((b * 16 + hh) * 2048 + tok) * 64 + d] =
                __float2bfloat16(val);
        }
      }
    }
  } else if constexpr (EPI == 6) {
    bf16* pout = (bf16*)C0 + (size_t)blockIdx.z * M * N;
    #pragma unroll
    for (int mc = 0; mc < 4; ++mc) {
      #pragma unroll
      for (int reg = 0; reg < 4; ++reg) {
        int m = m0 + wm + mc * 16 + ((lane >> 4) << 2) + reg;
        #pragma unroll
        for (int nc = 0; nc < 4; ++nc) {
          int n = n0 + wn + nc * 16 + (lane & 15);
          pout[(size_t)m * N + n] = __float2bfloat16(acc[mc][nc][reg]);
        }
      }
    }
  } else {
    #pragma unroll
    for (int mc = 0; mc < 4; ++mc) {
      #pragma unroll
      for (int reg = 0; reg < 4; ++reg) {
        int m = m0 + wm + mc * 16 + ((lane >> 4) << 2) + reg;
        #pragma unroll
        for (int nc = 0; nc < 4; ++nc) {
          int n = n0 + wn + nc * 16 + (lane & 15);
          float val = acc[mc][nc][reg] + bias0[n];
          size_t idx = (size_t)m * N + n;
          if constexpr (EPI == 3) {
            ((float*)C0)[idx] = val + resid[idx];
          } else if constexpr (EPI == 4) {
            ((bf16*)C0)[idx] = __float2bfloat16(gelu_f(val));
          } else {
            ((float*)C0)[idx] = gelu_f(val) + resid[idx];
          }
        }
      }
    }
  }
}

// ---------------- split-K reduce for MLP2: out = gelu(sum partials + b2) + out1
__global__ __launch_bounds__(256) void reduce_mlp2(
    const bf16* __restrict__ part, const float* __restrict__ b2,
    const float* __restrict__ out1, float* __restrict__ out) {
  const int row = blockIdx.x, t = threadIdx.x;
  const size_t base = (size_t)row * 1024 + t * 4;
  float sum[4] = {0.f, 0.f, 0.f, 0.f};
  #pragma unroll
  for (int kc = 0; kc < 4; ++kc) {
    ushort4 u = *(const ushort4*)(part + (size_t)kc * 4096 * 1024 + base);
    unsigned short us[4] = {u.x, u.y, u.z, u.w};
    #pragma unroll
    for (int j = 0; j < 4; ++j) {
      bf16 h;
      __builtin_memcpy(&h, &us[j], 2);
      sum[j] += __bfloat162float(h);
    }
  }
  float4 bv = ((const float4*)b2)[t];
  float4 rv = *(const float4*)(out1 + base);
  float4 o;
  o.x = gelu_f(sum[0] + bv.x) + rv.x;
  o.y = gelu_f(sum[1] + bv.y) + rv.y;
  o.z = gelu_f(sum[2] + bv.z) + rv.z;
  o.w = gelu_f(sum[3] + bv.w) + rv.w;
  *(float4*)(out + base) = o;
}

// ---------------- Flash attention, off-by-one softmax + head slimming
// q is PRESCALED by C=0.125*log2(e), so p = exp2(q.k) directly.
// Deferred reduction: per-lane running sum & max of p only; denominator
// = max_p + sum_p (identity: exp(a)/ (exp(amax)+sum exp(a))), one
// cross-lane reduce at the end. Double-buffered K/V staging (m97 pattern):
// one barrier per j-tile, staged loads land during the previous compute.
__global__ __launch_bounds__(256) void attn_kernel(
    const bf16* __restrict__ q, const bf16* __restrict__ k,
    const bf16* __restrict__ vt, const float* __restrict__ slim,
    bf16* __restrict__ attn) {
  __shared__ __align__(16) bf16 Ks[2][64][64];
  __shared__ __align__(16) bf16 Vs[2][64][64];
  __shared__ __align__(16) bf16 Ps[4][16][72];

  const int t = threadIdx.x, lane = t & 63, w = t >> 6;
  const int fr = lane & 15, qd = lane >> 4;
  const int bh = blockIdx.y;
  const int q0 = blockIdx.x * 64;
  const size_t bhbase = (size_t)bh * 2048 * 64;

  const int qrow = q0 + w * 16 + fr;
  const bf16* qp = q + bhbase + (size_t)qrow * 64 + qd * 8;
  bf16x8 qf0 = *(const bf16x8*)qp;
  bf16x8 qf1 = *(const bf16x8*)(qp + 32);

  const int srow = lane >> 3;   // 0..7 within 8-row chunk
  const int sg = lane & 7;      // LDS 16B-group position this lane fills

  f32x4 o_acc[4] = {};
  float m_lane[4] = {0.f, 0.f, 0.f, 0.f};   // max of p (p > 0)
  float l_lane[4] = {0.f, 0.f, 0.f, 0.f};

  auto stage = [&](int buf, int j0) {
    #pragma unroll
    for (int c = 0; c < 2; ++c) {
      int r = w * 16 + c * 8 + srow;
      int gk = sg ^ (r & 7);  // swizzled global group
      load16_lds(k + bhbase + (size_t)(j0 + r) * 64 + gk * 8,
                 &Ks[buf][w * 16 + c * 8][0]);
      load16_lds(vt + bhbase + (size_t)r * 2048 + j0 + gk * 8,
                 &Vs[buf][w * 16 + c * 8][0]);
    }
  };

  stage(0, 0);
  for (int it = 0; it < 32; ++it) {
    const int cur = it & 1;
    __syncthreads();  // drains stage(cur) (issued a full iteration ago)
    if (it + 1 < 32) stage(cur ^ 1, (it + 1) * 64);

    f32x4 z[4];
    #pragma unroll
    for (int nc = 0; nc < 4; ++nc) {
      int kr = nc * 16 + fr;
      bf16x8 kf0 = *(const bf16x8*)&Ks[cur][kr][(qd ^ (kr & 7)) * 8];
      bf16x8 kf1 = *(const bf16x8*)&Ks[cur][kr][((qd + 4) ^ (kr & 7)) * 8];
      f32x4 zz = {};
      zz = __builtin_amdgcn_mfma_f32_16x16x32_bf16(qf0, kf0, zz, 0, 0, 0);
      zz = __builtin_amdgcn_mfma_f32_16x16x32_bf16(qf1, kf1, zz, 0, 0, 0);
      z[nc] = zz;
    }

    #pragma unroll
    for (int nc = 0; nc < 4; ++nc)
      #pragma unroll
      for (int r = 0; r < 4; ++r) {
        float p = exp2f(z[nc][r]);
        l_lane[r] += p;
        m_lane[r] = fmaxf(m_lane[r], p);
        Ps[w][qd * 4 + r][nc * 16 + fr] = __float2bfloat16(p);
      }

    bf16x8 pf0 = *(const bf16x8*)&Ps[w][fr][qd * 8];
    bf16x8 pf1 = *(const bf16x8*)&Ps[w][fr][32 + qd * 8];
    #pragma unroll
    for (int dc = 0; dc < 4; ++dc) {
      int vr = dc * 16 + fr;
      bf16x8 vf0 = *(const bf16x8*)&Vs[cur][vr][(qd ^ (vr & 7)) * 8];
      bf16x8 vf1 = *(const bf16x8*)&Vs[cur][vr][((qd + 4) ^ (vr & 7)) * 8];
      o_acc[dc] = __builtin_amdgcn_mfma_f32_16x16x32_bf16(pf0, vf0, o_acc[dc], 0, 0, 0);
      o_acc[dc] = __builtin_amdgcn_mfma_f32_16x16x32_bf16(pf1, vf1, o_acc[dc], 0, 0, 0);
    }
  }

  #pragma unroll
  for (int off = 1; off <= 8; off <<= 1)
    #pragma unroll
    for (int r = 0; r < 4; ++r) {
      l_lane[r] += __shfl_xor(l_lane[r], off);
      m_lane[r] = fmaxf(m_lane[r], __shfl_xor(m_lane[r], off));
    }

  const int b = bh >> 4, hh = bh & 15;
  const float sl = slim[hh];
  #pragma unroll
  for (int r = 0; r < 4; ++r) {
    float inv = sl / (m_lane[r] + l_lane[r]);
    int mrow = b * 2048 + q0 + w * 16 + qd * 4 + r;
    #pragma unroll
    for (int dc = 0; dc < 4; ++dc) {
      int col = hh * 64 + dc * 16 + fr;
      attn[(size_t)mrow * 1024 + col] = __float2bfloat16(o_acc[dc][r] * inv);
    }
  }
}

extern "C" void kernel_launch(void* const* d_in, const int* in_sizes, int n_in,
                              void* d_out, int out_size, void* d_ws, size_t ws_size,
                              hipStream_t stream) {
  const float* x    = (const float*)d_in[0];
  const float* ln1g = (const float*)d_in[1];
  const float* ln1b = (const float*)d_in[2];
  const float* Wq   = (const float*)d_in[3];
  const float* bq   = (const float*)d_in[4];
  const float* Wk   = (const float*)d_in[5];
  const float* bk   = (const float*)d_in[6];
  const float* Wv   = (const float*)d_in[7];
  const float* bv   = (const float*)d_in[8];
  const float* Wo   = (const float*)d_in[9];
  const float* bo   = (const float*)d_in[10];
  const float* slim = (const float*)d_in[11];
  const float* ln2g = (const float*)d_in[12];
  const float* ln2b = (const float*)d_in[13];
  const float* W1   = (const float*)d_in[14];
  const float* b1   = (const float*)d_in[15];
  const float* W2   = (const float*)d_in[16];
  const float* b2   = (const float*)d_in[17];

  char* p = (char*)d_ws;
  auto take = [&](size_t nbytes) {
    char* r = p;
    p += (nbytes + 255) & ~(size_t)255;
    return r;
  };
  bf16* Wqkv_t = (bf16*)take((size_t)3072 * 1024 * 2);
  bf16* Wo_t = (bf16*)take((size_t)1024 * 1024 * 2);
  bf16* W1_t = (bf16*)take((size_t)4096 * 1024 * 2);
  bf16* W2_t = (bf16*)take((size_t)1024 * 4096 * 2);
  bf16* h1   = (bf16*)take((size_t)4096 * 1024 * 2);   // also partial[0]
  bf16* qb   = (bf16*)take((size_t)4096 * 1024 * 2);   // also partial[1]
  bf16* kb   = (bf16*)take((size_t)4096 * 1024 * 2);   // also partial[2]
  bf16* vtb  = (bf16*)take((size_t)4096 * 1024 * 2);   // also partial[3]
  bf16* attn = (bf16*)take((size_t)4096 * 1024 * 2);
  float* out1 = (float*)take((size_t)4096 * 1024 * 4);
  bf16* h2   = (bf16*)take((size_t)4096 * 1024 * 2);
  bf16* m1   = (bf16*)take((size_t)4096 * 4096 * 2);

  // h1..vtb are dead after attn_kernel; reuse as 4x bf16 split-K partials.
  bf16* parts = h1;

  dim3 blk(256);

  transpose_cast<<<dim3(32, 32), blk, 0, stream>>>(Wq, Wqkv_t, 1024, 1024);
  transpose_cast<<<dim3(32, 32), blk, 0, stream>>>(Wk, Wqkv_t + (size_t)1024 * 1024, 1024, 1024);
  transpose_cast<<<dim3(32, 32), blk, 0, stream>>>(Wv, Wqkv_t + (size_t)2048 * 1024, 1024, 1024);
  transpose_cast<<<dim3(32, 32), blk, 0, stream>>>(Wo, Wo_t, 1024, 1024);
  transpose_cast<<<dim3(128, 32), blk, 0, stream>>>(W1, W1_t, 1024, 4096);
  transpose_cast<<<dim3(32, 128), blk, 0, stream>>>(W2, W2_t, 4096, 1024);

  ln_kernel<<<4096, blk, 0, stream>>>(x, ln1g, ln1b, h1);

  // fused QKV: N = 3072 (q output prescaled by 0.125*log2e)
  gemm_bf16<0><<<dim3(24, 32), blk, 0, stream>>>(
      h1, Wqkv_t, bq, bk, bv, nullptr, qb, kb, vtb, 4096, 3072, 1024);

  attn_kernel<<<dim3(32, 32), blk, 0, stream>>>(qb, kb, vtb, slim, attn);

  gemm_bf16<3><<<dim3(8, 32), blk, 0, stream>>>(
      attn, Wo_t, bo, nullptr, nullptr, x, out1, nullptr, nullptr, 4096, 1024, 1024);

  ln_kernel<<<4096, blk, 0, stream>>>(out1, ln2g, ln2b, h2);

  gemm_bf16<4><<<dim3(32, 32), blk, 0, stream>>>(
      h2, W1_t, b1, nullptr, nullptr, nullptr, m1, nullptr, nullptr, 4096, 4096, 1024);

  // MLP2 split-K=4: 1024 blocks (4/CU), bf16 partials, then fused reduce
  gemm_bf16<6><<<dim3(8, 32, 4), blk, 0, stream>>>(
      m1, W2_t, nullptr, nullptr, nullptr, nullptr, parts, nullptr, nullptr,
      4096, 1024, 4096);
  reduce_mlp2<<<4096, blk, 0, stream>>>(parts, b2, out1, (float*)d_out);
}

// Round 7
// 435.334 us; speedup vs baseline: 1.0752x; 1.0752x over previous
//
#include <hip/hip_runtime.h>
#include <hip/hip_bf16.h>

typedef __hip_bfloat16 bf16;
typedef short bf16x8 __attribute__((ext_vector_type(8)));
typedef float f32x4 __attribute__((ext_vector_type(4)));

__device__ __forceinline__ float gelu_f(float x) {
  return 0.5f * x * (1.f + erff(x * 0.70710678118654752f));
}

__device__ __forceinline__ unsigned short f2bfu(float f) {
  bf16 h = __float2bfloat16(f);
  unsigned short u;
  __builtin_memcpy(&u, &h, 2);
  return u;
}

// async 16B/lane global->LDS; lds dest is wave-uniform base + lane*16
__device__ __forceinline__ void load16_lds(const bf16* g, bf16* l) {
  __builtin_amdgcn_global_load_lds(
      (const __attribute__((address_space(1))) unsigned int*)g,
      (__attribute__((address_space(3))) unsigned int*)l, 16, 0, 0);
}

// ---------------- weight transpose + cast: src fp32 [R][C] -> dst bf16 [C][R]
__global__ __launch_bounds__(256) void transpose_cast(
    const float* __restrict__ src, bf16* __restrict__ dst, int R, int C) {
  __shared__ float tile[32][33];
  int tx = threadIdx.x & 31, ty = threadIdx.x >> 5;  // 32 x 8
  int r0 = blockIdx.y * 32, c0 = blockIdx.x * 32;
  #pragma unroll
  for (int i = ty; i < 32; i += 8)
    tile[i][tx] = src[(size_t)(r0 + i) * C + (c0 + tx)];
  __syncthreads();
  #pragma unroll
  for (int i = ty; i < 32; i += 8)
    dst[(size_t)(c0 + i) * R + (r0 + tx)] = __float2bfloat16(tile[tx][i]);
}

// ---------------- LayerNorm: x fp32 [rows][1024] -> y bf16, one block per row
__global__ __launch_bounds__(256) void ln_kernel(
    const float* __restrict__ x, const float* __restrict__ g,
    const float* __restrict__ b, bf16* __restrict__ y) {
  int row = blockIdx.x;
  int t = threadIdx.x;
  const float4* xr = (const float4*)(x + (size_t)row * 1024);
  float4 v = xr[t];
  float s = v.x + v.y + v.z + v.w;
  float ss = v.x * v.x + v.y * v.y + v.z * v.z + v.w * v.w;
  #pragma unroll
  for (int off = 32; off >= 1; off >>= 1) {
    s += __shfl_xor(s, off);
    ss += __shfl_xor(ss, off);
  }
  __shared__ float red[8];
  int wv = t >> 6;
  if ((t & 63) == 0) { red[wv] = s; red[4 + wv] = ss; }
  __syncthreads();
  float S = red[0] + red[1] + red[2] + red[3];
  float SS = red[4] + red[5] + red[6] + red[7];
  float mu = S * (1.f / 1024.f);
  float var = SS * (1.f / 1024.f) - mu * mu;
  float inv = rsqrtf(var + 1e-5f);
  float4 gv = ((const float4*)g)[t];
  float4 bv = ((const float4*)b)[t];
  ushort4 o;
  o.x = f2bfu((v.x - mu) * inv * gv.x + bv.x);
  o.y = f2bfu((v.y - mu) * inv * gv.y + bv.y);
  o.z = f2bfu((v.z - mu) * inv * gv.z + bv.z);
  o.w = f2bfu((v.w - mu) * inv * gv.w + bv.w);
  ((ushort4*)(y + (size_t)row * 1024))[t] = o;
}

// ---------------- GEMM: C = A[M][K] @ Bt[N][K]^T + bias
// m97 pattern: global_load_lds width-16 staging, non-padded LDS, XOR swizzle,
// double-buffered prefetch.
// EPI 0: fused QKV epilogue; q output prescaled by C=0.125*log2(e) so the
//        attention kernel can use exp2 with no multiply.
// EPI 3: fp32 out = val + resid
// EPI 4: bf16 out = gelu(val)
// EPI 5: fp32 out = gelu(val) + resid
// EPI 6: split-K partial: bf16 partial[z][m][n] = acc (no bias), K-chunk=1024
template <int EPI>
__global__ __launch_bounds__(256) void gemm_bf16(
    const bf16* __restrict__ A, const bf16* __restrict__ Bt,
    const float* __restrict__ bias0, const float* __restrict__ bias1,
    const float* __restrict__ bias2, const float* __restrict__ resid,
    void* __restrict__ C0, void* __restrict__ C1, void* __restrict__ C2,
    int M, int N, int K) {
  __shared__ __align__(16) bf16 As[2][128 * 32];
  __shared__ __align__(16) bf16 Bs[2][128 * 32];
  const int t = threadIdx.x, lane = t & 63, w = t >> 6;
  const int wm = (w >> 1) * 64, wn = (w & 1) * 64;
  const int m0 = blockIdx.y * 128, n0 = blockIdx.x * 128;

  const int koff = (EPI == 6) ? (int)blockIdx.z * 1024 : 0;
  const int kc_len = (EPI == 6) ? 1024 : K;

  const int srow = lane >> 2;   // row within 16-row staging chunk
  const int sgrp = lane & 3;    // LDS col-group position this lane fills
  f32x4 acc[4][4] = {};

  const bf16* Abase = A + (size_t)m0 * K + koff;
  const bf16* Bbase = Bt + (size_t)n0 * K + koff;

  auto stage = [&](int buf, int kt) {
    #pragma unroll
    for (int c = 0; c < 2; ++c) {
      int row = w * 32 + c * 16 + srow;
      int sw = (row & 3) ^ ((row >> 2) & 3);
      int gg = sgrp ^ sw;  // global col-group this lane fetches (swizzled)
      const bf16* ga = Abase + (size_t)row * K + kt + gg * 8;
      const bf16* gb = Bbase + (size_t)row * K + kt + gg * 8;
      load16_lds(ga, &As[buf][(w * 32 + c * 16) * 32]);
      load16_lds(gb, &Bs[buf][(w * 32 + c * 16) * 32]);
    }
  };

  // fragment read col-group (swizzle inverse), uniform over mc/nc:
  // row = (mult of 16) + (lane&15) -> sw = (lane&3)^((lane>>2)&3)
  const int q8 = (((lane >> 4) ^ (lane & 3) ^ ((lane >> 2) & 3))) * 8;
  const int fr = lane & 15;

  const int nk = kc_len >> 5;
  stage(0, 0);
  for (int i = 0; i < nk; ++i) {
    const int cur = i & 1;
    __syncthreads();  // drains vmcnt (staged loads for cur) + barrier
    if (i + 1 < nk) stage(cur ^ 1, (i + 1) << 5);
    bf16x8 af[4], bfr[4];
    #pragma unroll
    for (int mc = 0; mc < 4; ++mc)
      af[mc] = *(const bf16x8*)&As[cur][(wm + mc * 16 + fr) * 32 + q8];
    #pragma unroll
    for (int nc = 0; nc < 4; ++nc)
      bfr[nc] = *(const bf16x8*)&Bs[cur][(wn + nc * 16 + fr) * 32 + q8];
    #pragma unroll
    for (int mc = 0; mc < 4; ++mc)
      #pragma unroll
      for (int nc = 0; nc < 4; ++nc)
        acc[mc][nc] = __builtin_amdgcn_mfma_f32_16x16x32_bf16(
            af[mc], bfr[nc], acc[mc][nc], 0, 0, 0);
  }

  if constexpr (EPI == 0) {
    const int which = n0 >> 10;  // block-uniform: 0=q, 1=k, 2=v
    const float* bp = which == 0 ? bias0 : which == 1 ? bias1 : bias2;
    bf16* qk = (bf16*)(which == 0 ? C0 : C1);
    const float qscale = 0.18033688011112042f;  // 0.125 * log2(e)
    #pragma unroll
    for (int mc = 0; mc < 4; ++mc) {
      #pragma unroll
      for (int reg = 0; reg < 4; ++reg) {
        int m = m0 + wm + mc * 16 + ((lane >> 4) << 2) + reg;
        int b = m >> 11, tok = m & 2047;
        #pragma unroll
        for (int nc = 0; nc < 4; ++nc) {
          int n = n0 + wn + nc * 16 + (lane & 15);
          int nn = n & 1023, hh = nn >> 6, d = n & 63;
          float val = acc[mc][nc][reg] + bp[nn];
          if (which == 2)
            ((bf16*)C2)[(size_t)((b * 16 + hh) * 64 + d) * 2048 + tok] =
                __float2bfloat16(val);
          else if (which == 0)
            qk[(size_t)((b * 16 + hh) * 2048 + tok) * 64 + d] =
                __float2bfloat16(val * qscale);
          else
            qk[(size_t)((b * 16 + hh) * 2048 + tok) * 64 + d] =
                __float2bfloat16(val);
        }
      }
    }
  } else if constexpr (EPI == 6) {
    bf16* pout = (bf16*)C0 + (size_t)blockIdx.z * M * N;
    #pragma unroll
    for (int mc = 0; mc < 4; ++mc) {
      #pragma unroll
      for (int reg = 0; reg < 4; ++reg) {
        int m = m0 + wm + mc * 16 + ((lane >> 4) << 2) + reg;
        #pragma unroll
        for (int nc = 0; nc < 4; ++nc) {
          int n = n0 + wn + nc * 16 + (lane & 15);
          pout[(size_t)m * N + n] = __float2bfloat16(acc[mc][nc][reg]);
        }
      }
    }
  } else {
    #pragma unroll
    for (int mc = 0; mc < 4; ++mc) {
      #pragma unroll
      for (int reg = 0; reg < 4; ++reg) {
        int m = m0 + wm + mc * 16 + ((lane >> 4) << 2) + reg;
        #pragma unroll
        for (int nc = 0; nc < 4; ++nc) {
          int n = n0 + wn + nc * 16 + (lane & 15);
          float val = acc[mc][nc][reg] + bias0[n];
          size_t idx = (size_t)m * N + n;
          if constexpr (EPI == 3) {
            ((float*)C0)[idx] = val + resid[idx];
          } else if constexpr (EPI == 4) {
            ((bf16*)C0)[idx] = __float2bfloat16(gelu_f(val));
          } else {
            ((float*)C0)[idx] = gelu_f(val) + resid[idx];
          }
        }
      }
    }
  }
}

// ---------------- split-K reduce for MLP2: out = gelu(sum partials + b2) + out1
__global__ __launch_bounds__(256) void reduce_mlp2(
    const bf16* __restrict__ part, const float* __restrict__ b2,
    const float* __restrict__ out1, float* __restrict__ out) {
  const int row = blockIdx.x, t = threadIdx.x;
  const size_t base = (size_t)row * 1024 + t * 4;
  float sum[4] = {0.f, 0.f, 0.f, 0.f};
  #pragma unroll
  for (int kc = 0; kc < 4; ++kc) {
    ushort4 u = *(const ushort4*)(part + (size_t)kc * 4096 * 1024 + base);
    unsigned short us[4] = {u.x, u.y, u.z, u.w};
    #pragma unroll
    for (int j = 0; j < 4; ++j) {
      bf16 h;
      __builtin_memcpy(&h, &us[j], 2);
      sum[j] += __bfloat162float(h);
    }
  }
  float4 bv = ((const float4*)b2)[t];
  float4 rv = *(const float4*)(out1 + base);
  float4 o;
  o.x = gelu_f(sum[0] + bv.x) + rv.x;
  o.y = gelu_f(sum[1] + bv.y) + rv.y;
  o.z = gelu_f(sum[2] + bv.z) + rv.z;
  o.w = gelu_f(sum[3] + bv.w) + rv.w;
  *(float4*)(out + base) = o;
}

// ---------------- Flash attention, off-by-one softmax + head slimming
// q is PRESCALED by C=0.125*log2(e), so p = exp2(q.k) directly.
// Deferred reduction: per-lane running sum & max of p; denom = max_p + sum_p,
// one cross-lane reduce at the end.
// Staging: REGISTER prefetch + single padded LDS buffer (no global_load_lds,
// so ds_write dest is free -> +8 pad kills bank conflicts, no swizzle).
// Loop: ds_write(regs); B1; gload(next); compute; B2  -- the B2 vmcnt drain
// sees loads issued a compute-phase earlier (m97-style slack), B1 sees none.
__global__ __launch_bounds__(256) void attn_kernel(
    const bf16* __restrict__ q, const bf16* __restrict__ k,
    const bf16* __restrict__ vt, const float* __restrict__ slim,
    bf16* __restrict__ attn) {
  __shared__ __align__(16) bf16 Ks[64][72];
  __shared__ __align__(16) bf16 Vs[64][72];
  __shared__ __align__(16) bf16 Ps[4][16][72];

  const int t = threadIdx.x, lane = t & 63, w = t >> 6;
  const int fr = lane & 15, qd = lane >> 4;
  const int bh = blockIdx.y;
  const int q0 = blockIdx.x * 64;
  const size_t bhbase = (size_t)bh * 2048 * 64;

  const int qrow = q0 + w * 16 + fr;
  const bf16* qp = q + bhbase + (size_t)qrow * 64 + qd * 8;
  bf16x8 qf0 = *(const bf16x8*)qp;
  bf16x8 qf1 = *(const bf16x8*)(qp + 32);

  // staging mapping: 256 threads cover 64 rows x 8 groups in 2 chunks
  const int r0 = t >> 3, g0 = t & 7;
  const bf16* kbase = k + bhbase + (size_t)r0 * 64 + g0 * 8;
  const bf16* vbase = vt + bhbase + (size_t)r0 * 2048 + g0 * 8;

  bf16x8 kreg0, kreg1, vreg0, vreg1;
  auto gload = [&](int j0) {
    kreg0 = *(const bf16x8*)(kbase + (size_t)j0 * 64);
    kreg1 = *(const bf16x8*)(kbase + (size_t)(j0 + 32) * 64);
    vreg0 = *(const bf16x8*)(vbase + j0);
    vreg1 = *(const bf16x8*)(vbase + (size_t)32 * 2048 + j0);
  };
  gload(0);

  f32x4 o_acc[4] = {};
  float m_lane[4] = {0.f, 0.f, 0.f, 0.f};   // max of p (p > 0)
  float l_lane[4] = {0.f, 0.f, 0.f, 0.f};

  for (int it = 0; it < 32; ++it) {
    // commit regs (tile it) to LDS; waits vmcnt for loads issued last iter
    *(bf16x8*)&Ks[r0][g0 * 8] = kreg0;
    *(bf16x8*)&Ks[r0 + 32][g0 * 8] = kreg1;
    *(bf16x8*)&Vs[r0][g0 * 8] = vreg0;
    *(bf16x8*)&Vs[r0 + 32][g0 * 8] = vreg1;
    __syncthreads();  // B1: writes visible; no outstanding vmem
    if (it + 1 < 32) gload((it + 1) * 64);

    f32x4 z[4];
    #pragma unroll
    for (int nc = 0; nc < 4; ++nc) {
      int kr = nc * 16 + fr;
      bf16x8 kf0 = *(const bf16x8*)&Ks[kr][qd * 8];
      bf16x8 kf1 = *(const bf16x8*)&Ks[kr][32 + qd * 8];
      f32x4 zz = {};
      zz = __builtin_amdgcn_mfma_f32_16x16x32_bf16(qf0, kf0, zz, 0, 0, 0);
      zz = __builtin_amdgcn_mfma_f32_16x16x32_bf16(qf1, kf1, zz, 0, 0, 0);
      z[nc] = zz;
    }

    #pragma unroll
    for (int nc = 0; nc < 4; ++nc)
      #pragma unroll
      for (int r = 0; r < 4; ++r) {
        float p = exp2f(z[nc][r]);
        l_lane[r] += p;
        m_lane[r] = fmaxf(m_lane[r], p);
        Ps[w][qd * 4 + r][nc * 16 + fr] = __float2bfloat16(p);
      }

    bf16x8 pf0 = *(const bf16x8*)&Ps[w][fr][qd * 8];
    bf16x8 pf1 = *(const bf16x8*)&Ps[w][fr][32 + qd * 8];
    #pragma unroll
    for (int dc = 0; dc < 4; ++dc) {
      int vr = dc * 16 + fr;
      bf16x8 vf0 = *(const bf16x8*)&Vs[vr][qd * 8];
      bf16x8 vf1 = *(const bf16x8*)&Vs[vr][32 + qd * 8];
      o_acc[dc] = __builtin_amdgcn_mfma_f32_16x16x32_bf16(pf0, vf0, o_acc[dc], 0, 0, 0);
      o_acc[dc] = __builtin_amdgcn_mfma_f32_16x16x32_bf16(pf1, vf1, o_acc[dc], 0, 0, 0);
    }
    __syncthreads();  // B2: reads done before next overwrite; drains gload
                      // issued a full compute-phase ago
  }

  #pragma unroll
  for (int off = 1; off <= 8; off <<= 1)
    #pragma unroll
    for (int r = 0; r < 4; ++r) {
      l_lane[r] += __shfl_xor(l_lane[r], off);
      m_lane[r] = fmaxf(m_lane[r], __shfl_xor(m_lane[r], off));
    }

  const int b = bh >> 4, hh = bh & 15;
  const float sl = slim[hh];
  #pragma unroll
  for (int r = 0; r < 4; ++r) {
    float inv = sl / (m_lane[r] + l_lane[r]);
    int mrow = b * 2048 + q0 + w * 16 + qd * 4 + r;
    #pragma unroll
    for (int dc = 0; dc < 4; ++dc) {
      int col = hh * 64 + dc * 16 + fr;
      attn[(size_t)mrow * 1024 + col] = __float2bfloat16(o_acc[dc][r] * inv);
    }
  }
}

extern "C" void kernel_launch(void* const* d_in, const int* in_sizes, int n_in,
                              void* d_out, int out_size, void* d_ws, size_t ws_size,
                              hipStream_t stream) {
  const float* x    = (const float*)d_in[0];
  const float* ln1g = (const float*)d_in[1];
  const float* ln1b = (const float*)d_in[2];
  const float* Wq   = (const float*)d_in[3];
  const float* bq   = (const float*)d_in[4];
  const float* Wk   = (const float*)d_in[5];
  const float* bk   = (const float*)d_in[6];
  const float* Wv   = (const float*)d_in[7];
  const float* bv   = (const float*)d_in[8];
  const float* Wo   = (const float*)d_in[9];
  const float* bo   = (const float*)d_in[10];
  const float* slim = (const float*)d_in[11];
  const float* ln2g = (const float*)d_in[12];
  const float* ln2b = (const float*)d_in[13];
  const float* W1   = (const float*)d_in[14];
  const float* b1   = (const float*)d_in[15];
  const float* W2   = (const float*)d_in[16];
  const float* b2   = (const float*)d_in[17];

  char* p = (char*)d_ws;
  auto take = [&](size_t nbytes) {
    char* r = p;
    p += (nbytes + 255) & ~(size_t)255;
    return r;
  };
  bf16* Wqkv_t = (bf16*)take((size_t)3072 * 1024 * 2);
  bf16* Wo_t = (bf16*)take((size_t)1024 * 1024 * 2);
  bf16* W1_t = (bf16*)take((size_t)4096 * 1024 * 2);
  bf16* W2_t = (bf16*)take((size_t)1024 * 4096 * 2);
  bf16* h1   = (bf16*)take((size_t)4096 * 1024 * 2);   // also partial[0]
  bf16* qb   = (bf16*)take((size_t)4096 * 1024 * 2);   // also partial[1]
  bf16* kb   = (bf16*)take((size_t)4096 * 1024 * 2);   // also partial[2]
  bf16* vtb  = (bf16*)take((size_t)4096 * 1024 * 2);   // also partial[3]
  bf16* attn = (bf16*)take((size_t)4096 * 1024 * 2);
  float* out1 = (float*)take((size_t)4096 * 1024 * 4);
  bf16* h2   = (bf16*)take((size_t)4096 * 1024 * 2);
  bf16* m1   = (bf16*)take((size_t)4096 * 4096 * 2);

  // h1..vtb are dead after attn_kernel; reuse as 4x bf16 split-K partials.
  bf16* parts = h1;

  dim3 blk(256);

  transpose_cast<<<dim3(32, 32), blk, 0, stream>>>(Wq, Wqkv_t, 1024, 1024);
  transpose_cast<<<dim3(32, 32), blk, 0, stream>>>(Wk, Wqkv_t + (size_t)1024 * 1024, 1024, 1024);
  transpose_cast<<<dim3(32, 32), blk, 0, stream>>>(Wv, Wqkv_t + (size_t)2048 * 1024, 1024, 1024);
  transpose_cast<<<dim3(32, 32), blk, 0, stream>>>(Wo, Wo_t, 1024, 1024);
  transpose_cast<<<dim3(128, 32), blk, 0, stream>>>(W1, W1_t, 1024, 4096);
  transpose_cast<<<dim3(32, 128), blk, 0, stream>>>(W2, W2_t, 4096, 1024);

  ln_kernel<<<4096, blk, 0, stream>>>(x, ln1g, ln1b, h1);

  // fused QKV: N = 3072 (q output prescaled by 0.125*log2e)
  gemm_bf16<0><<<dim3(24, 32), blk, 0, stream>>>(
      h1, Wqkv_t, bq, bk, bv, nullptr, qb, kb, vtb, 4096, 3072, 1024);

  attn_kernel<<<dim3(32, 32), blk, 0, stream>>>(qb, kb, vtb, slim, attn);

  gemm_bf16<3><<<dim3(8, 32), blk, 0, stream>>>(
      attn, Wo_t, bo, nullptr, nullptr, x, out1, nullptr, nullptr, 4096, 1024, 1024);

  ln_kernel<<<4096, blk, 0, stream>>>(out1, ln2g, ln2b, h2);

  gemm_bf16<4><<<dim3(32, 32), blk, 0, stream>>>(
      h2, W1_t, b1, nullptr, nullptr, nullptr, m1, nullptr, nullptr, 4096, 4096, 1024);

  // MLP2 split-K=4: 1024 blocks (4/CU), bf16 partials, then fused reduce
  gemm_bf16<6><<<dim3(8, 32, 4), blk, 0, stream>>>(
      m1, W2_t, nullptr, nullptr, nullptr, nullptr, parts, nullptr, nullptr,
      4096, 1024, 4096);
  reduce_mlp2<<<4096, blk, 0, stream>>>(parts, b2, out1, (float*)d_out);
}

// Round 8
// 431.216 us; speedup vs baseline: 1.0854x; 1.0096x over previous
//
#include <hip/hip_runtime.h>
#include <hip/hip_bf16.h>

typedef __hip_bfloat16 bf16;
typedef short bf16x8 __attribute__((ext_vector_type(8)));
typedef short bf16x4 __attribute__((ext_vector_type(4)));
typedef float f32x4 __attribute__((ext_vector_type(4)));

__device__ __forceinline__ float gelu_f(float x) {
  return 0.5f * x * (1.f + erff(x * 0.70710678118654752f));
}

__device__ __forceinline__ unsigned short f2bfu(float f) {
  bf16 h = __float2bfloat16(f);
  unsigned short u;
  __builtin_memcpy(&u, &h, 2);
  return u;
}

// async 16B/lane global->LDS; lds dest is wave-uniform base + lane*16
__device__ __forceinline__ void load16_lds(const bf16* g, bf16* l) {
  __builtin_amdgcn_global_load_lds(
      (const __attribute__((address_space(1))) unsigned int*)g,
      (__attribute__((address_space(3))) unsigned int*)l, 16, 0, 0);
}

// ---------------- weight transpose + cast: src fp32 [R][C] -> dst bf16 [C][R]
__global__ __launch_bounds__(256) void transpose_cast(
    const float* __restrict__ src, bf16* __restrict__ dst, int R, int C) {
  __shared__ float tile[32][33];
  int tx = threadIdx.x & 31, ty = threadIdx.x >> 5;  // 32 x 8
  int r0 = blockIdx.y * 32, c0 = blockIdx.x * 32;
  #pragma unroll
  for (int i = ty; i < 32; i += 8)
    tile[i][tx] = src[(size_t)(r0 + i) * C + (c0 + tx)];
  __syncthreads();
  #pragma unroll
  for (int i = ty; i < 32; i += 8)
    dst[(size_t)(c0 + i) * R + (r0 + tx)] = __float2bfloat16(tile[tx][i]);
}

// ---------------- LayerNorm: x fp32 [rows][1024] -> y bf16, one block per row
__global__ __launch_bounds__(256) void ln_kernel(
    const float* __restrict__ x, const float* __restrict__ g,
    const float* __restrict__ b, bf16* __restrict__ y) {
  int row = blockIdx.x;
  int t = threadIdx.x;
  const float4* xr = (const float4*)(x + (size_t)row * 1024);
  float4 v = xr[t];
  float s = v.x + v.y + v.z + v.w;
  float ss = v.x * v.x + v.y * v.y + v.z * v.z + v.w * v.w;
  #pragma unroll
  for (int off = 32; off >= 1; off >>= 1) {
    s += __shfl_xor(s, off);
    ss += __shfl_xor(ss, off);
  }
  __shared__ float red[8];
  int wv = t >> 6;
  if ((t & 63) == 0) { red[wv] = s; red[4 + wv] = ss; }
  __syncthreads();
  float S = red[0] + red[1] + red[2] + red[3];
  float SS = red[4] + red[5] + red[6] + red[7];
  float mu = S * (1.f / 1024.f);
  float var = SS * (1.f / 1024.f) - mu * mu;
  float inv = rsqrtf(var + 1e-5f);
  float4 gv = ((const float4*)g)[t];
  float4 bv = ((const float4*)b)[t];
  ushort4 o;
  o.x = f2bfu((v.x - mu) * inv * gv.x + bv.x);
  o.y = f2bfu((v.y - mu) * inv * gv.y + bv.y);
  o.z = f2bfu((v.z - mu) * inv * gv.z + bv.z);
  o.w = f2bfu((v.w - mu) * inv * gv.w + bv.w);
  ((ushort4*)(y + (size_t)row * 1024))[t] = o;
}

// ---------------- GEMM: C = A[M][K] @ Bt[N][K]^T + bias
// m97 pattern: global_load_lds width-16 staging, non-padded LDS, XOR swizzle,
// double-buffered prefetch.
// EPI 0: fused QKV epilogue; q output prescaled by C=0.125*log2(e) so the
//        attention kernel can use exp2 with no multiply.
// EPI 3: fp32 out = val + resid
// EPI 4: bf16 out = gelu(val)
// EPI 5: fp32 out = gelu(val) + resid
// EPI 6: split-K partial: bf16 partial[z][m][n] = acc (no bias), K-chunk=1024
template <int EPI>
__global__ __launch_bounds__(256) void gemm_bf16(
    const bf16* __restrict__ A, const bf16* __restrict__ Bt,
    const float* __restrict__ bias0, const float* __restrict__ bias1,
    const float* __restrict__ bias2, const float* __restrict__ resid,
    void* __restrict__ C0, void* __restrict__ C1, void* __restrict__ C2,
    int M, int N, int K) {
  __shared__ __align__(16) bf16 As[2][128 * 32];
  __shared__ __align__(16) bf16 Bs[2][128 * 32];
  const int t = threadIdx.x, lane = t & 63, w = t >> 6;
  const int wm = (w >> 1) * 64, wn = (w & 1) * 64;
  const int m0 = blockIdx.y * 128, n0 = blockIdx.x * 128;

  const int koff = (EPI == 6) ? (int)blockIdx.z * 1024 : 0;
  const int kc_len = (EPI == 6) ? 1024 : K;

  const int srow = lane >> 2;   // row within 16-row staging chunk
  const int sgrp = lane & 3;    // LDS col-group position this lane fills
  f32x4 acc[4][4] = {};

  const bf16* Abase = A + (size_t)m0 * K + koff;
  const bf16* Bbase = Bt + (size_t)n0 * K + koff;

  auto stage = [&](int buf, int kt) {
    #pragma unroll
    for (int c = 0; c < 2; ++c) {
      int row = w * 32 + c * 16 + srow;
      int sw = (row & 3) ^ ((row >> 2) & 3);
      int gg = sgrp ^ sw;  // global col-group this lane fetches (swizzled)
      const bf16* ga = Abase + (size_t)row * K + kt + gg * 8;
      const bf16* gb = Bbase + (size_t)row * K + kt + gg * 8;
      load16_lds(ga, &As[buf][(w * 32 + c * 16) * 32]);
      load16_lds(gb, &Bs[buf][(w * 32 + c * 16) * 32]);
    }
  };

  // fragment read col-group (swizzle inverse), uniform over mc/nc:
  // row = (mult of 16) + (lane&15) -> sw = (lane&3)^((lane>>2)&3)
  const int q8 = (((lane >> 4) ^ (lane & 3) ^ ((lane >> 2) & 3))) * 8;
  const int fr = lane & 15;

  const int nk = kc_len >> 5;
  stage(0, 0);
  for (int i = 0; i < nk; ++i) {
    const int cur = i & 1;
    __syncthreads();  // drains vmcnt (staged loads for cur) + barrier
    if (i + 1 < nk) stage(cur ^ 1, (i + 1) << 5);
    bf16x8 af[4], bfr[4];
    #pragma unroll
    for (int mc = 0; mc < 4; ++mc)
      af[mc] = *(const bf16x8*)&As[cur][(wm + mc * 16 + fr) * 32 + q8];
    #pragma unroll
    for (int nc = 0; nc < 4; ++nc)
      bfr[nc] = *(const bf16x8*)&Bs[cur][(wn + nc * 16 + fr) * 32 + q8];
    #pragma unroll
    for (int mc = 0; mc < 4; ++mc)
      #pragma unroll
      for (int nc = 0; nc < 4; ++nc)
        acc[mc][nc] = __builtin_amdgcn_mfma_f32_16x16x32_bf16(
            af[mc], bfr[nc], acc[mc][nc], 0, 0, 0);
  }

  if constexpr (EPI == 0) {
    const int which = n0 >> 10;  // block-uniform: 0=q, 1=k, 2=v
    const float* bp = which == 0 ? bias0 : which == 1 ? bias1 : bias2;
    bf16* qk = (bf16*)(which == 0 ? C0 : C1);
    const float qscale = 0.18033688011112042f;  // 0.125 * log2(e)
    #pragma unroll
    for (int mc = 0; mc < 4; ++mc) {
      #pragma unroll
      for (int reg = 0; reg < 4; ++reg) {
        int m = m0 + wm + mc * 16 + ((lane >> 4) << 2) + reg;
        int b = m >> 11, tok = m & 2047;
        #pragma unroll
        for (int nc = 0; nc < 4; ++nc) {
          int n = n0 + wn + nc * 16 + (lane & 15);
          int nn = n & 1023, hh = nn >> 6, d = n & 63;
          float val = acc[mc][nc][reg] + bp[nn];
          if (which == 2)
            ((bf16*)C2)[(size_t)((b * 16 + hh) * 64 + d) * 2048 + tok] =
                __float2bfloat16(val);
          else if (which == 0)
            qk[(size_t)((b * 16 + hh) * 2048 + tok) * 64 + d] =
                __float2bfloat16(val * qscale);
          else
            qk[(size_t)((b * 16 + hh) * 2048 + tok) * 64 + d] =
                __float2bfloat16(val);
        }
      }
    }
  } else if constexpr (EPI == 6) {
    bf16* pout = (bf16*)C0 + (size_t)blockIdx.z * M * N;
    #pragma unroll
    for (int mc = 0; mc < 4; ++mc) {
      #pragma unroll
      for (int reg = 0; reg < 4; ++reg) {
        int m = m0 + wm + mc * 16 + ((lane >> 4) << 2) + reg;
        #pragma unroll
        for (int nc = 0; nc < 4; ++nc) {
          int n = n0 + wn + nc * 16 + (lane & 15);
          pout[(size_t)m * N + n] = __float2bfloat16(acc[mc][nc][reg]);
        }
      }
    }
  } else {
    #pragma unroll
    for (int mc = 0; mc < 4; ++mc) {
      #pragma unroll
      for (int reg = 0; reg < 4; ++reg) {
        int m = m0 + wm + mc * 16 + ((lane >> 4) << 2) + reg;
        #pragma unroll
        for (int nc = 0; nc < 4; ++nc) {
          int n = n0 + wn + nc * 16 + (lane & 15);
          float val = acc[mc][nc][reg] + bias0[n];
          size_t idx = (size_t)m * N + n;
          if constexpr (EPI == 3) {
            ((float*)C0)[idx] = val + resid[idx];
          } else if constexpr (EPI == 4) {
            ((bf16*)C0)[idx] = __float2bfloat16(gelu_f(val));
          } else {
            ((float*)C0)[idx] = gelu_f(val) + resid[idx];
          }
        }
      }
    }
  }
}

// ---------------- split-K reduce for MLP2: out = gelu(sum partials + b2) + out1
__global__ __launch_bounds__(256) void reduce_mlp2(
    const bf16* __restrict__ part, const float* __restrict__ b2,
    const float* __restrict__ out1, float* __restrict__ out) {
  const int row = blockIdx.x, t = threadIdx.x;
  const size_t base = (size_t)row * 1024 + t * 4;
  float sum[4] = {0.f, 0.f, 0.f, 0.f};
  #pragma unroll
  for (int kc = 0; kc < 4; ++kc) {
    ushort4 u = *(const ushort4*)(part + (size_t)kc * 4096 * 1024 + base);
    unsigned short us[4] = {u.x, u.y, u.z, u.w};
    #pragma unroll
    for (int j = 0; j < 4; ++j) {
      bf16 h;
      __builtin_memcpy(&h, &us[j], 2);
      sum[j] += __bfloat162float(h);
    }
  }
  float4 bv = ((const float4*)b2)[t];
  float4 rv = *(const float4*)(out1 + base);
  float4 o;
  o.x = gelu_f(sum[0] + bv.x) + rv.x;
  o.y = gelu_f(sum[1] + bv.y) + rv.y;
  o.z = gelu_f(sum[2] + bv.z) + rv.z;
  o.w = gelu_f(sum[3] + bv.w) + rv.w;
  *(float4*)(out + base) = o;
}

// ---------------- Flash attention, off-by-one softmax + head slimming
// q is PRESCALED by C=0.125*log2(e), so p = exp2(q.k) directly.
// S^T TRICK: QK is computed as mfma(kf, qf) -> S^T fragments, so each lane
// holds 4 CONSECUTIVE KEYS for one fixed q-row (row = fr). P values pack
// into a single ds_write_b64 per nc (4 writes/tile instead of 16 b16), and
// l/m become per-lane scalars (4 indep chains), reduced over qd (xor 16/32)
// once at the end. Ps layout [row][key] is unchanged -> PV side untouched.
// Staging: register prefetch + single padded LDS (R7 pattern).
__global__ __launch_bounds__(256) void attn_kernel(
    const bf16* __restrict__ q, const bf16* __restrict__ k,
    const bf16* __restrict__ vt, const float* __restrict__ slim,
    bf16* __restrict__ attn) {
  __shared__ __align__(16) bf16 Ks[64][72];
  __shared__ __align__(16) bf16 Vs[64][72];
  __shared__ __align__(16) bf16 Ps[4][16][72];

  const int t = threadIdx.x, lane = t & 63, w = t >> 6;
  const int fr = lane & 15, qd = lane >> 4;
  const int bh = blockIdx.y;
  const int q0 = blockIdx.x * 64;
  const size_t bhbase = (size_t)bh * 2048 * 64;

  const int qrow = q0 + w * 16 + fr;
  const bf16* qp = q + bhbase + (size_t)qrow * 64 + qd * 8;
  bf16x8 qf0 = *(const bf16x8*)qp;
  bf16x8 qf1 = *(const bf16x8*)(qp + 32);

  // staging mapping: 256 threads cover 64 rows x 8 groups in 2 chunks
  const int r0 = t >> 3, g0 = t & 7;
  const bf16* kbase = k + bhbase + (size_t)r0 * 64 + g0 * 8;
  const bf16* vbase = vt + bhbase + (size_t)r0 * 2048 + g0 * 8;

  bf16x8 kreg0, kreg1, vreg0, vreg1;
  auto gload = [&](int j0) {
    kreg0 = *(const bf16x8*)(kbase + (size_t)j0 * 64);
    kreg1 = *(const bf16x8*)(kbase + (size_t)(j0 + 32) * 64);
    vreg0 = *(const bf16x8*)(vbase + j0);
    vreg1 = *(const bf16x8*)(vbase + (size_t)32 * 2048 + j0);
  };
  gload(0);

  f32x4 o_acc[4] = {};
  float m4[4] = {0.f, 0.f, 0.f, 0.f};  // per-nc max of p for row fr
  float l4[4] = {0.f, 0.f, 0.f, 0.f};  // per-nc sum of p for row fr

  for (int it = 0; it < 32; ++it) {
    *(bf16x8*)&Ks[r0][g0 * 8] = kreg0;
    *(bf16x8*)&Ks[r0 + 32][g0 * 8] = kreg1;
    *(bf16x8*)&Vs[r0][g0 * 8] = vreg0;
    *(bf16x8*)&Vs[r0 + 32][g0 * 8] = vreg1;
    __syncthreads();  // B1: writes visible; no outstanding vmem
    if (it + 1 < 32) gload((it + 1) * 64);

    // S^T = K Q^T: z[nc][r] = S[qrow=fr][key = nc*16 + qd*4 + r]
    f32x4 z[4];
    #pragma unroll
    for (int nc = 0; nc < 4; ++nc) {
      int kr = nc * 16 + fr;
      bf16x8 kf0 = *(const bf16x8*)&Ks[kr][qd * 8];
      bf16x8 kf1 = *(const bf16x8*)&Ks[kr][32 + qd * 8];
      f32x4 zz = {};
      zz = __builtin_amdgcn_mfma_f32_16x16x32_bf16(kf0, qf0, zz, 0, 0, 0);
      zz = __builtin_amdgcn_mfma_f32_16x16x32_bf16(kf1, qf1, zz, 0, 0, 0);
      z[nc] = zz;
    }

    #pragma unroll
    for (int nc = 0; nc < 4; ++nc) {
      float p0 = exp2f(z[nc][0]);
      float p1 = exp2f(z[nc][1]);
      float p2 = exp2f(z[nc][2]);
      float p3 = exp2f(z[nc][3]);
      l4[nc] += (p0 + p1) + (p2 + p3);
      m4[nc] = fmaxf(m4[nc], fmaxf(fmaxf(p0, p1), fmaxf(p2, p3)));
      bf16x4 pk;
      pk[0] = (short)f2bfu(p0);
      pk[1] = (short)f2bfu(p1);
      pk[2] = (short)f2bfu(p2);
      pk[3] = (short)f2bfu(p3);
      *(bf16x4*)&Ps[w][fr][nc * 16 + qd * 4] = pk;  // 4 consecutive keys
    }

    // Ps is per-wave: intra-wave lgkmcnt ordering suffices
    bf16x8 pf0 = *(const bf16x8*)&Ps[w][fr][qd * 8];
    bf16x8 pf1 = *(const bf16x8*)&Ps[w][fr][32 + qd * 8];
    #pragma unroll
    for (int dc = 0; dc < 4; ++dc) {
      int vr = dc * 16 + fr;
      bf16x8 vf0 = *(const bf16x8*)&Vs[vr][qd * 8];
      bf16x8 vf1 = *(const bf16x8*)&Vs[vr][32 + qd * 8];
      o_acc[dc] = __builtin_amdgcn_mfma_f32_16x16x32_bf16(pf0, vf0, o_acc[dc], 0, 0, 0);
      o_acc[dc] = __builtin_amdgcn_mfma_f32_16x16x32_bf16(pf1, vf1, o_acc[dc], 0, 0, 0);
    }
    __syncthreads();  // B2: K/V reads done before next overwrite; drains gload
  }

  // combine per-nc chains, reduce over qd (lanes fr, fr+16, fr+32, fr+48)
  float l_all = (l4[0] + l4[1]) + (l4[2] + l4[3]);
  float m_all = fmaxf(fmaxf(m4[0], m4[1]), fmaxf(m4[2], m4[3]));
  l_all += __shfl_xor(l_all, 16);
  m_all = fmaxf(m_all, __shfl_xor(m_all, 16));
  l_all += __shfl_xor(l_all, 32);
  m_all = fmaxf(m_all, __shfl_xor(m_all, 32));
  // lane i (i<16) now holds totals for row w*16+i (replicated over qd)

  const int b = bh >> 4, hh = bh & 15;
  const float sl = slim[hh];
  #pragma unroll
  for (int r = 0; r < 4; ++r) {
    float lr = __shfl(l_all, qd * 4 + r);
    float mr = __shfl(m_all, qd * 4 + r);
    float inv = sl / (mr + lr);
    int mrow = b * 2048 + q0 + w * 16 + qd * 4 + r;
    #pragma unroll
    for (int dc = 0; dc < 4; ++dc) {
      int col = hh * 64 + dc * 16 + fr;
      attn[(size_t)mrow * 1024 + col] = __float2bfloat16(o_acc[dc][r] * inv);
    }
  }
}

extern "C" void kernel_launch(void* const* d_in, const int* in_sizes, int n_in,
                              void* d_out, int out_size, void* d_ws, size_t ws_size,
                              hipStream_t stream) {
  const float* x    = (const float*)d_in[0];
  const float* ln1g = (const float*)d_in[1];
  const float* ln1b = (const float*)d_in[2];
  const float* Wq   = (const float*)d_in[3];
  const float* bq   = (const float*)d_in[4];
  const float* Wk   = (const float*)d_in[5];
  const float* bk   = (const float*)d_in[6];
  const float* Wv   = (const float*)d_in[7];
  const float* bv   = (const float*)d_in[8];
  const float* Wo   = (const float*)d_in[9];
  const float* bo   = (const float*)d_in[10];
  const float* slim = (const float*)d_in[11];
  const float* ln2g = (const float*)d_in[12];
  const float* ln2b = (const float*)d_in[13];
  const float* W1   = (const float*)d_in[14];
  const float* b1   = (const float*)d_in[15];
  const float* W2   = (const float*)d_in[16];
  const float* b2   = (const float*)d_in[17];

  char* p = (char*)d_ws;
  auto take = [&](size_t nbytes) {
    char* r = p;
    p += (nbytes + 255) & ~(size_t)255;
    return r;
  };
  bf16* Wqkv_t = (bf16*)take((size_t)3072 * 1024 * 2);
  bf16* Wo_t = (bf16*)take((size_t)1024 * 1024 * 2);
  bf16* W1_t = (bf16*)take((size_t)4096 * 1024 * 2);
  bf16* W2_t = (bf16*)take((size_t)1024 * 4096 * 2);
  bf16* h1   = (bf16*)take((size_t)4096 * 1024 * 2);   // also partial[0]
  bf16* qb   = (bf16*)take((size_t)4096 * 1024 * 2);   // also partial[1]
  bf16* kb   = (bf16*)take((size_t)4096 * 1024 * 2);   // also partial[2]
  bf16* vtb  = (bf16*)take((size_t)4096 * 1024 * 2);   // also partial[3]
  bf16* attn = (bf16*)take((size_t)4096 * 1024 * 2);
  float* out1 = (float*)take((size_t)4096 * 1024 * 4);
  bf16* h2   = (bf16*)take((size_t)4096 * 1024 * 2);
  bf16* m1   = (bf16*)take((size_t)4096 * 4096 * 2);

  // h1..vtb are dead after attn_kernel; reuse as 4x bf16 split-K partials.
  bf16* parts = h1;

  dim3 blk(256);

  transpose_cast<<<dim3(32, 32), blk, 0, stream>>>(Wq, Wqkv_t, 1024, 1024);
  transpose_cast<<<dim3(32, 32), blk, 0, stream>>>(Wk, Wqkv_t + (size_t)1024 * 1024, 1024, 1024);
  transpose_cast<<<dim3(32, 32), blk, 0, stream>>>(Wv, Wqkv_t + (size_t)2048 * 1024, 1024, 1024);
  transpose_cast<<<dim3(32, 32), blk, 0, stream>>>(Wo, Wo_t, 1024, 1024);
  transpose_cast<<<dim3(128, 32), blk, 0, stream>>>(W1, W1_t, 1024, 4096);
  transpose_cast<<<dim3(32, 128), blk, 0, stream>>>(W2, W2_t, 4096, 1024);

  ln_kernel<<<4096, blk, 0, stream>>>(x, ln1g, ln1b, h1);

  // fused QKV: N = 3072 (q output prescaled by 0.125*log2e)
  gemm_bf16<0><<<dim3(24, 32), blk, 0, stream>>>(
      h1, Wqkv_t, bq, bk, bv, nullptr, qb, kb, vtb, 4096, 3072, 1024);

  attn_kernel<<<dim3(32, 32), blk, 0, stream>>>(qb, kb, vtb, slim, attn);

  gemm_bf16<3><<<dim3(8, 32), blk, 0, stream>>>(
      attn, Wo_t, bo, nullptr, nullptr, x, out1, nullptr, nullptr, 4096, 1024, 1024);

  ln_kernel<<<4096, blk, 0, stream>>>(out1, ln2g, ln2b, h2);

  gemm_bf16<4><<<dim3(32, 32), blk, 0, stream>>>(
      h2, W1_t, b1, nullptr, nullptr, nullptr, m1, nullptr, nullptr, 4096, 4096, 1024);

  // MLP2 split-K=4: 1024 blocks (4/CU), bf16 partials, then fused reduce
  gemm_bf16<6><<<dim3(8, 32, 4), blk, 0, stream>>>(
      m1, W2_t, nullptr, nullptr, nullptr, nullptr, parts, nullptr, nullptr,
      4096, 1024, 4096);
  reduce_mlp2<<<4096, blk, 0, stream>>>(parts, b2, out1, (float*)d_out);
}